// Round 2
// baseline (573.622 us; speedup 1.0000x reference)
//
#include <hip/hip_runtime.h>
#include <hip/hip_bf16.h>

#define N_NODES 65536
#define N_EDGES 1048576
#define IN_DIM 96
#define HID 128
#define OUTD 256
#define N_ACT 20

typedef unsigned short u16;
typedef unsigned char u8;
typedef unsigned int u32;
typedef __attribute__((ext_vector_type(8))) short bf16x8;
typedef __attribute__((ext_vector_type(4))) float f32x4;
typedef __attribute__((ext_vector_type(2))) float f32x2;

// intermediates bf16 (xr/hres) and fp8-e4m3 (xl, gather-path) ; all math fp32
__device__ __forceinline__ float bf2f(u16 v) { return __uint_as_float(((u32)v) << 16); }
__device__ __forceinline__ u16 f2bf(float f) {
    u32 x = __float_as_uint(f);
    return (u16)((x + 0x7fffu + ((x >> 16) & 1u)) >> 16);
}

// ---- fp8 via HW converters (V_CVT_PK_*) ----
__device__ __forceinline__ u8 ftofp8_hw(float f) {
    return (u8)((u32)__builtin_amdgcn_cvt_pk_fp8_f32(f, f, 0, false) & 0xffu);
}

// ---- DPP adds on the VALU pipe (ctrl must be a constant -> template) ----
template <int CTRL>
__device__ __forceinline__ float dppadd(float p) {
    return p + __uint_as_float((u32)__builtin_amdgcn_update_dpp(
        0, (int)__float_as_uint(p), CTRL, 0xF, 0xF, true));
}
// full-wave sum, result broadcast (readlane 63)
__device__ __forceinline__ float wave_sum_bcast(float p) {
    p = dppadd<0x111>(p);   // row_shr:1
    p = dppadd<0x112>(p);   // row_shr:2
    p = dppadd<0x114>(p);   // row_shr:4
    p = dppadd<0x118>(p);   // row_shr:8
    p = dppadd<0x142>(p);   // row_bcast15
    p = dppadd<0x143>(p);   // row_bcast31
    return __uint_as_float((u32)__builtin_amdgcn_readlane((int)__float_as_uint(p), 63));
}
// 16-lane (hw-row) sum, broadcast to all 16 lanes of the row.
__device__ __forceinline__ float red16(float p) {
    p = dppadd<0xB1>(p);
    p = dppadd<0x4E>(p);
    p = dppadd<0x141>(p);
    p = dppadd<0x140>(p);
    return p;
}

// ---------------- prep: zero deg + bf16 n-major weights + MFMA-pack Wq ----------------
__global__ __launch_bounds__(256) void k_prep(
    int* __restrict__ deg,
    const float* __restrict__ Wl, const float* __restrict__ Wr, const float* __restrict__ Wres,
    u16* __restrict__ wt,
    const float* __restrict__ W0, u16* __restrict__ wt0,
    const float* __restrict__ W1, u16* __restrict__ wt1,
    const float* __restrict__ Wq, u16* __restrict__ wqB)
{
    int b = blockIdx.x, t = threadIdx.x;
    if (b < 256) {
        deg[b * 256 + t] = 0;
    } else if (b < 640) {
        int idx = (b - 256) * 256 + t;        // 0..98303  gat weights [768][128]
        int nn = idx >> 7, k = idx & 127;
        float v;
        if (nn < 256) v = Wl[k * OUTD + nn];
        else if (nn < 512) v = Wr[k * OUTD + (nn - 256)];
        else v = Wres[k * OUTD + (nn - 512)];
        wt[idx] = f2bf(v);
    } else if (b < 688) {
        int idx = (b - 640) * 256 + t;        // 0..12287  W0^T [128][96]
        int nn = idx / 96, k = idx - nn * 96;
        wt0[idx] = f2bf(W0[k * HID + nn]);
    } else if (b < 752) {
        int idx = (b - 688) * 256 + t;        // 0..16383  W1^T [128][128]
        int nn = idx >> 7, k = idx & 127;
        wt1[idx] = f2bf(W1[k * HID + nn]);
    } else {
        // Wq packed into MFMA 16x16x32 B-fragment layout:
        // wqB[((tile*8 + kk)*64 + lane)*8 + j] = Wq[kk*32 + (lane>>4)*8 + j][tile*16 + (lane&15)]
        int idx = (b - 752) * 256 + t;        // 0..8191
        int tile = idx >> 12, rem = idx & 4095;
        int kk = rem >> 9, ln = (rem >> 3) & 63, j = idx & 7;
        int k = kk * 32 + (ln >> 4) * 8 + j;
        int q = tile * 16 + (ln & 15);
        wqB[idx] = (q < N_ACT) ? f2bf(Wq[k * N_ACT + q]) : (u16)0;
    }
}

// ---------------- exclusive scan of degrees -> CSR offsets (int4-vectorized) ----------------
__global__ __launch_bounds__(1024) void k_scan(const int* __restrict__ deg, int* __restrict__ off) {
    __shared__ int part[1024];
    int t = threadIdx.x;
    int base = t * 64;
    const int4* d4 = (const int4*)(deg + base);
    int s = 0;
#pragma unroll
    for (int i = 0; i < 16; i++) { int4 v = d4[i]; s += v.x + v.y + v.z + v.w; }
    part[t] = s;
    __syncthreads();
    for (int o = 1; o < 1024; o <<= 1) {
        int v = (t >= o) ? part[t - o] : 0;
        __syncthreads();
        part[t] += v;
        __syncthreads();
    }
    int run = (t == 0) ? 0 : part[t - 1];
    int4* o4 = (int4*)(off + base);
#pragma unroll
    for (int i = 0; i < 16; i++) {
        int4 v = d4[i];
        int4 w;
        w.x = run;
        w.y = run + v.x;
        w.z = w.y + v.y;
        w.w = w.z + v.z;
        run = w.w + v.w;
        o4[i] = w;
    }
    if (t == 1023) off[N_NODES] = run;
}

// ---------------- scatter edge records into CSR order (atomic-free: rank from deg pass) ----------------
__global__ __launch_bounds__(256) void k_scatter(
    const int* __restrict__ ei, const float* __restrict__ ea,
    const int* __restrict__ off, const int* __restrict__ rank,
    int4* __restrict__ erec)
{
    int e = blockIdx.x * 256 + threadIdx.x;
    int src = ei[e];
    int dst = ei[N_EDGES + e];
    float a0 = ea[e * 3 + 0];
    float a1 = ea[e * 3 + 1];
    float a2 = ea[e * 3 + 2];
    int pos = off[dst] + rank[e];
    erec[pos] = make_int4(src, __float_as_int(a0), __float_as_int(a1), __float_as_int(a2));
}

// ---------------- fused node pipeline (MFMA): MLP(2x LN) -> xl8/xr/hres, + deg/rank fold ----------------
// Block-parity interleave: even blocks = MLP (1024), odd blocks = degree/rank (1024 x 4 edges/thread),
// so MFMA-heavy and atomic-latency-heavy waves co-reside on every CU from t=0.
__global__ __launch_bounds__(256, 4) void k_fused(
    const float* __restrict__ in,
    const u16* __restrict__ wt0, const u16* __restrict__ wt1, const u16* __restrict__ wt,
    const float* __restrict__ b0, const float* __restrict__ g0, const float* __restrict__ be0,
    const float* __restrict__ b1, const float* __restrict__ g1, const float* __restrict__ be1,
    const float* __restrict__ bl, const float* __restrict__ br, const float* __restrict__ gbias,
    const int* __restrict__ ei, int* __restrict__ deg, int* __restrict__ rank,
    u8* __restrict__ xl8, u16* __restrict__ xr, u16* __restrict__ hres)
{
    if (blockIdx.x & 1) {
        // rank pass: 4 edges per thread, int4-vectorized loads/stores, 4 atomics in flight
        int t4 = (blockIdx.x >> 1) * 256 + threadIdx.x;      // 0..262143
        int4 dv = ((const int4*)(ei + N_EDGES))[t4];
        int4 rv;
        rv.x = atomicAdd(deg + dv.x, 1);
        rv.y = atomicAdd(deg + dv.y, 1);
        rv.z = atomicAdd(deg + dv.z, 1);
        rv.w = atomicAdd(deg + dv.w, 1);
        ((int4*)rank)[t4] = rv;
        return;
    }
    int mb = blockIdx.x >> 1;                                // 0..1023
    int wid = threadIdx.x >> 6, lane = threadIdx.x & 63;
    int l15 = lane & 15, quad = lane >> 4;
    int m0 = (mb * 4 + wid) * 16;

    __shared__ u16 xbuf[4][16][136];   // per-wave x-strip (bf16)

    f32x4 acc[8];

    // ===== layer 0: [16 x 96] @ W0 -> [16 x 128], relu + LN =====
#pragma unroll
    for (int t = 0; t < 8; t++) acc[t] = {0.f, 0.f, 0.f, 0.f};
#pragma unroll
    for (int kk = 0; kk < 3; kk++) {
        const float* ap = in + (long)(m0 + l15) * IN_DIM + kk * 32 + quad * 8;
        float4 fa = *(const float4*)(ap);
        float4 fb = *(const float4*)(ap + 4);
        bf16x8 af;
        af[0] = (short)f2bf(fa.x); af[1] = (short)f2bf(fa.y);
        af[2] = (short)f2bf(fa.z); af[3] = (short)f2bf(fa.w);
        af[4] = (short)f2bf(fb.x); af[5] = (short)f2bf(fb.y);
        af[6] = (short)f2bf(fb.z); af[7] = (short)f2bf(fb.w);
#pragma unroll
        for (int t = 0; t < 8; t++) {
            bf16x8 bf = *(const bf16x8*)(wt0 + (t * 16 + l15) * IN_DIM + kk * 32 + quad * 8);
            acc[t] = __builtin_amdgcn_mfma_f32_16x16x32_bf16(af, bf, acc[t], 0, 0, 0);
        }
    }
    {
        float bv[8], gv[8], bev[8];
#pragma unroll
        for (int t = 0; t < 8; t++) {
            int col = t * 16 + l15;
            bv[t] = b0[col]; gv[t] = g0[col]; bev[t] = be0[col];
        }
#pragma unroll
        for (int g = 0; g < 4; g++) {
            float s_ = 0.f, q_ = 0.f;
#pragma unroll
            for (int t = 0; t < 8; t++) {
                float x = fmaxf(acc[t][g] + bv[t], 0.f);
                acc[t][g] = x;
                s_ += x;
                q_ = fmaf(x, x, q_);
            }
            s_ = red16(s_);
            q_ = red16(q_);
            float mu = s_ * (1.f / HID);
            float var = q_ * (1.f / HID) - mu * mu;
            float rs = rsqrtf(fmaxf(var, 0.f) + 1e-5f);
#pragma unroll
            for (int t = 0; t < 8; t++) {
                float y = (acc[t][g] - mu) * rs * gv[t] + bev[t];
                xbuf[wid][quad * 4 + g][t * 16 + l15] = f2bf(y);
            }
        }
    }

    // ===== layer 1: [16 x 128] @ W1 -> [16 x 128], relu + LN =====
#pragma unroll
    for (int t = 0; t < 8; t++) acc[t] = {0.f, 0.f, 0.f, 0.f};
#pragma unroll
    for (int kk = 0; kk < 4; kk++) {
        bf16x8 af = *(const bf16x8*)(&xbuf[wid][l15][kk * 32 + quad * 8]);
#pragma unroll
        for (int t = 0; t < 8; t++) {
            bf16x8 bf = *(const bf16x8*)(wt1 + (t * 16 + l15) * HID + kk * 32 + quad * 8);
            acc[t] = __builtin_amdgcn_mfma_f32_16x16x32_bf16(af, bf, acc[t], 0, 0, 0);
        }
    }
    {
        float bv[8], gv[8], bev[8];
#pragma unroll
        for (int t = 0; t < 8; t++) {
            int col = t * 16 + l15;
            bv[t] = b1[col]; gv[t] = g1[col]; bev[t] = be1[col];
        }
#pragma unroll
        for (int g = 0; g < 4; g++) {
            float s_ = 0.f, q_ = 0.f;
#pragma unroll
            for (int t = 0; t < 8; t++) {
                float x = fmaxf(acc[t][g] + bv[t], 0.f);
                acc[t][g] = x;
                s_ += x;
                q_ = fmaf(x, x, q_);
            }
            s_ = red16(s_);
            q_ = red16(q_);
            float mu = s_ * (1.f / HID);
            float var = q_ * (1.f / HID) - mu * mu;
            float rs = rsqrtf(fmaxf(var, 0.f) + 1e-5f);
#pragma unroll
            for (int t = 0; t < 8; t++) {
                float y = (acc[t][g] - mu) * rs * gv[t] + bev[t];
                xbuf[wid][quad * 4 + g][t * 16 + l15] = f2bf(y);
            }
        }
    }

    // ===== projections: x1 @ {Wl|Wr|Wres} + bias -> xl8(fp8 HW)/xr/hres =====
    // split into 2 halves of 8 col-tiles each: accumulator regs 64 -> 32, total ~96/wave
    for (int nT = 0; nT < 3; nT++) {
        for (int h = 0; h < 2; h++) {
            f32x4 pacc[8];
#pragma unroll
            for (int t = 0; t < 8; t++) pacc[t] = {0.f, 0.f, 0.f, 0.f};
#pragma unroll
            for (int kk = 0; kk < 4; kk++) {
                bf16x8 af = *(const bf16x8*)(&xbuf[wid][l15][kk * 32 + quad * 8]);
#pragma unroll
                for (int t = 0; t < 8; t++) {
                    bf16x8 bf = *(const bf16x8*)(wt + (long)(nT * 256 + h * 128 + t * 16 + l15) * HID + kk * 32 + quad * 8);
                    pacc[t] = __builtin_amdgcn_mfma_f32_16x16x32_bf16(af, bf, pacc[t], 0, 0, 0);
                }
            }
            if (nT == 0) {
#pragma unroll
                for (int t = 0; t < 8; t++) {
                    int col = h * 128 + t * 16 + l15;
                    float bvv = bl[col];
#pragma unroll
                    for (int g = 0; g < 4; g++) {
                        xl8[(long)(m0 + quad * 4 + g) * OUTD + col] = ftofp8_hw(pacc[t][g] + bvv);
                    }
                }
            } else {
                const float* bias = (nT == 1) ? br : gbias;
                u16* dst = (nT == 1) ? xr : hres;
#pragma unroll
                for (int t = 0; t < 8; t++) {
                    int col = h * 128 + t * 16 + l15;
                    float bvv = bias[col];
#pragma unroll
                    for (int g = 0; g < 4; g++) {
                        dst[(long)(m0 + quad * 4 + g) * OUTD + col] = f2bf(pacc[t][g] + bvv);
                    }
                }
            }
        }
    }
}

// ---------------- fused aggregation: register-staged CSR records (readlane broadcast), ----------------
// 8-deep xl8 value-prefetch queue, DPP wave-sum, fp8 HW pair-decode, MFMA head matmul.
__global__ __launch_bounds__(256, 5) void k_agg_fused(
    const int* __restrict__ off, const int4* __restrict__ erec,
    const u8* __restrict__ xl8, const u16* __restrict__ xr, const u16* __restrict__ hres,
    const float* __restrict__ We, const float* __restrict__ att,
    const float* __restrict__ g2, const float* __restrict__ be2,
    const u16* __restrict__ wqB, const float* __restrict__ bq,
    float* __restrict__ out)
{
    int wid = threadIdx.x >> 6, lane = threadIdx.x & 63;
    int n = blockIdx.x * 4 + wid;
    int j0 = lane * 4;
    __shared__ __align__(16) u16 ylds[4][256];

    const float LOG2E = 1.44269504088896f;

    float4 w0 = *(const float4*)(We + j0);
    float4 w1 = *(const float4*)(We + OUTD + j0);
    float4 w2 = *(const float4*)(We + 2 * OUTD + j0);
    float4 avf = *(const float4*)(att + j0);
    f32x2 w0_01 = {w0.x, w0.y}, w0_23 = {w0.z, w0.w};
    f32x2 w1_01 = {w1.x, w1.y}, w1_23 = {w1.z, w1.w};
    f32x2 w2_01 = {w2.x, w2.y}, w2_23 = {w2.z, w2.w};
    // fold log2(e) into att: softmax exp becomes a single native v_exp_f32 (2^x)
    f32x2 av01 = {avf.x * LOG2E, avf.y * LOG2E};
    f32x2 av23 = {avf.z * LOG2E, avf.w * LOG2E};

    ushort4 xrv = *(const ushort4*)(xr + (long)n * OUTD + j0);
    f32x2 xr01 = {bf2f(xrv.x), bf2f(xrv.y)};
    f32x2 xr23 = {bf2f(xrv.z), bf2f(xrv.w)};

    int beg = off[n], end = off[n + 1];
    int cnt = end - beg;

    float s = 0.f;
    f32x2 a01 = {0.f, 0.f}, a23 = {0.f, 0.f};

    if (cnt > 0) {
        const u8* xbase = xl8 + j0;
        // record staging: lane l of rc holds edge record beg+chunk+l (clamped to end-1)
        int4 rc = erec[min(beg + lane, end - 1)];
        int4 rn = rc;

        // 8-deep value queue: V[j] holds xl8 word for edge (chunk + k + j)
        u32 V[8];
#pragma unroll
        for (int j = 0; j < 8; j++) {
            int src = __builtin_amdgcn_readlane(rc.x, j);   // clamped records -> always valid
            V[j] = *(const u32*)(xbase + (long)src * OUTD);
        }

        for (int base = 0; base < cnt; base += 64) {
            if (cnt > base + 64)
                rn = erec[min(beg + base + 64 + lane, end - 1)];
            int m = min(64, cnt - base);
            int mr = (m + 7) & ~7;
            for (int k = 0; k < mr; k += 8) {
                float p[8];
                u32 vk[8];
#pragma unroll
                for (int j = 0; j < 8; j++) {
                    int kj = k + j;                         // 0..63
                    float ea0 = __int_as_float(__builtin_amdgcn_readlane(rc.y, kj));
                    float ea1 = __int_as_float(__builtin_amdgcn_readlane(rc.z, kj));
                    float ea2 = __int_as_float(__builtin_amdgcn_readlane(rc.w, kj));
                    u32 v = V[j];
                    vk[j] = v;
                    // refill slot j for edge base+kj+8 (record from rc or next chunk rn)
                    int tj = base + kj + 8;
                    if (tj < cnt) {
                        int rl = kj + 8;                    // 8..71
                        int srcn = (rl < 64) ? __builtin_amdgcn_readlane(rc.x, rl)
                                             : __builtin_amdgcn_readlane(rn.x, rl - 64);
                        V[j] = *(const u32*)(xbase + (long)srcn * OUTD);
                    }
                    // logit (log2 domain)
                    f32x2 d0 = __builtin_amdgcn_cvt_pk_f32_fp8((int)v, false);
                    f32x2 d1 = __builtin_amdgcn_cvt_pk_f32_fp8((int)v, true);
                    f32x2 ea0v = {ea0, ea0}, ea1v = {ea1, ea1}, ea2v = {ea2, ea2};
                    f32x2 t01 = d0 + xr01;
                    t01 = __builtin_elementwise_fma(ea0v, w0_01, t01);
                    t01 = __builtin_elementwise_fma(ea1v, w1_01, t01);
                    t01 = __builtin_elementwise_fma(ea2v, w2_01, t01);
                    f32x2 t23 = d1 + xr23;
                    t23 = __builtin_elementwise_fma(ea0v, w0_23, t23);
                    t23 = __builtin_elementwise_fma(ea1v, w1_23, t23);
                    t23 = __builtin_elementwise_fma(ea2v, w2_23, t23);
                    f32x2 l01 = __builtin_elementwise_max(t01, 0.2f * t01);
                    f32x2 l23 = __builtin_elementwise_max(t23, 0.2f * t23);
                    f32x2 pv = l01 * av01;
                    pv = __builtin_elementwise_fma(l23, av23, pv);
                    p[j] = pv[0] + pv[1];
                }
#pragma unroll
                for (int j = 0; j < 8; j++) p[j] = wave_sum_bcast(p[j]);
#pragma unroll
                for (int j = 0; j < 8; j++) {
                    if (base + k + j >= cnt) p[j] = -1.0e30f;   // pad edges -> exp2 = 0
                    float e = __builtin_amdgcn_exp2f(p[j]);
                    s += e;
                    f32x2 d0 = __builtin_amdgcn_cvt_pk_f32_fp8((int)vk[j], false);
                    f32x2 d1 = __builtin_amdgcn_cvt_pk_f32_fp8((int)vk[j], true);
                    f32x2 ev = {e, e};
                    a01 = __builtin_elementwise_fma(ev, d0, a01);
                    a23 = __builtin_elementwise_fma(ev, d1, a23);
                }
            }
            rc = rn;
        }
    }

    float inv = (cnt > 0) ? 1.f / s : 0.f;

    ushort4 hv = *(const ushort4*)(hres + (long)n * OUTD + j0);
    float h0 = fmaxf(fmaf(a01[0], inv, bf2f(hv.x)), 0.f);
    float h1 = fmaxf(fmaf(a01[1], inv, bf2f(hv.y)), 0.f);
    float h2 = fmaxf(fmaf(a23[0], inv, bf2f(hv.z)), 0.f);
    float h3 = fmaxf(fmaf(a23[1], inv, bf2f(hv.w)), 0.f);

    float sum = h0 + h1 + h2 + h3;
    float sq = h0 * h0 + h1 * h1 + h2 * h2 + h3 * h3;
    sum = wave_sum_bcast(sum);
    sq = wave_sum_bcast(sq);
    float mu = sum * (1.f / OUTD);
    float var = sq * (1.f / OUTD) - mu * mu;
    float rs = rsqrtf(fmaxf(var, 0.f) + 1e-5f);

    float4 gv = *(const float4*)(g2 + j0);
    float4 bv = *(const float4*)(be2 + j0);
    ushort4 yy;
    yy.x = f2bf((h0 - mu) * rs * gv.x + bv.x);
    yy.y = f2bf((h1 - mu) * rs * gv.y + bv.y);
    yy.z = f2bf((h2 - mu) * rs * gv.z + bv.z);
    yy.w = f2bf((h3 - mu) * rs * gv.w + bv.w);
    *(ushort4*)(&ylds[wid][j0]) = yy;
    __syncthreads();

    // ===== head: q = y @ Wq + bq via one MFMA pass (wave0: cols 0-15, wave1: cols 16-19) =====
    if (wid < 2) {
        int row = lane & 15, qd = lane >> 4;
        const u16* ab = &ylds[row & 3][qd * 8];   // rows 4-15 duplicate rows 0-3 (unused C rows)
        f32x4 cacc = {0.f, 0.f, 0.f, 0.f};
#pragma unroll
        for (int kk = 0; kk < 8; kk++) {
            bf16x8 afrag = *(const bf16x8*)(ab + kk * 32);
            bf16x8 bfrag = *(const bf16x8*)(wqB + ((((wid << 3) + kk) << 6) + lane) * 8);
            cacc = __builtin_amdgcn_mfma_f32_16x16x32_bf16(afrag, bfrag, cacc, 0, 0, 0);
        }
        // C layout: col=lane&15, row=(lane>>4)*4+g; lanes 0-15 hold rows(=nodes) 0-3 in g
        if (lane < 16) {
            int q = wid * 16 + lane;
            if (q < N_ACT) {
                float bqv = bq[q];
                long nb = (long)blockIdx.x * 4;
#pragma unroll
                for (int g = 0; g < 4; g++)
                    out[(nb + g) * N_ACT + q] = cacc[g] + bqv;
            }
        }
    }
}

extern "C" void kernel_launch(void* const* d_in, const int* in_sizes, int n_in,
                              void* d_out, int out_size, void* d_ws, size_t ws_size,
                              hipStream_t stream) {
    (void)in_sizes; (void)n_in; (void)out_size; (void)ws_size;
    const float* inp  = (const float*)d_in[0];
    const int*   ei   = (const int*)d_in[1];
    const float* ea   = (const float*)d_in[2];
    const float* W0   = (const float*)d_in[3];
    const float* b0   = (const float*)d_in[4];
    const float* g0   = (const float*)d_in[5];
    const float* be0  = (const float*)d_in[6];
    const float* W1   = (const float*)d_in[7];
    const float* b1   = (const float*)d_in[8];
    const float* g1   = (const float*)d_in[9];
    const float* be1  = (const float*)d_in[10];
    const float* Wl   = (const float*)d_in[11];
    const float* bl   = (const float*)d_in[12];
    const float* Wr   = (const float*)d_in[13];
    const float* br   = (const float*)d_in[14];
    const float* We   = (const float*)d_in[15];
    const float* att  = (const float*)d_in[16];
    const float* Wres = (const float*)d_in[17];
    const float* gbias= (const float*)d_in[18];
    const float* g2   = (const float*)d_in[19];
    const float* be2  = (const float*)d_in[20];
    const float* Wq   = (const float*)d_in[21];
    const float* bq   = (const float*)d_in[22];
    float* out = (float*)d_out;

    char* ws = (char*)d_ws;
    size_t o = 0;
    auto alloc = [&](size_t bytes) -> void* {
        void* p = ws + o;
        o += (bytes + 255) & ~(size_t)255;
        return p;
    };
    u8*    xl8    = (u8*)   alloc((size_t)N_NODES * OUTD);        // 16 MiB (fp8 e4m3)
    u16*   xr     = (u16*)  alloc((size_t)N_NODES * OUTD * 2);    // 32 MiB
    u16*   hres   = (u16*)  alloc((size_t)N_NODES * OUTD * 2);    // 32 MiB
    int*   deg    = (int*)  alloc((size_t)N_NODES * 4);           // 256 KiB
    int*   off    = (int*)  alloc((size_t)(N_NODES + 1) * 4);
    int*   rank   = (int*)  alloc((size_t)N_EDGES * 4);           // 4 MiB (edge slot from deg pass)
    int4*  erec   = (int4*) alloc((size_t)N_EDGES * 16);          // 16 MiB
    u16*   wt     = (u16*)  alloc((size_t)768 * HID * 2);         // 192 KiB  gat [768][128]
    u16*   wt0    = (u16*)  alloc((size_t)HID * IN_DIM * 2);      // 24 KiB   W0^T [128][96]
    u16*   wt1    = (u16*)  alloc((size_t)HID * HID * 2);         // 32 KiB   W1^T [128][128]
    u16*   wqB    = (u16*)  alloc((size_t)2 * 8 * 64 * 8 * 2);    // 16 KiB   Wq MFMA B-frags

    k_prep<<<784, 256, 0, stream>>>(deg, Wl, Wr, Wres, wt, W0, wt0, W1, wt1, Wq, wqB);
    k_fused<<<2048, 256, 0, stream>>>(inp, wt0, wt1, wt,
        b0, g0, be0, b1, g1, be1, bl, br, gbias, ei, deg, rank, xl8, xr, hres);
    k_scan<<<1, 1024, 0, stream>>>(deg, off);
    k_scatter<<<N_EDGES / 256, 256, 0, stream>>>(ei, ea, off, rank, erec);
    k_agg_fused<<<N_NODES / 4, 256, 0, stream>>>(off, erec, xl8, xr, hres, We, att, g2, be2, wqB, bq, out);
}

// Round 4
// 493.218 us; speedup vs baseline: 1.1630x; 1.1630x over previous
//
#include <hip/hip_runtime.h>
#include <hip/hip_bf16.h>

#define N_NODES 65536
#define N_EDGES 1048576
#define IN_DIM 96
#define HID 128
#define OUTD 256
#define N_ACT 20

typedef unsigned short u16;
typedef unsigned char u8;
typedef unsigned int u32;
typedef __attribute__((ext_vector_type(8))) short bf16x8;
typedef __attribute__((ext_vector_type(4))) float f32x4;
typedef __attribute__((ext_vector_type(2))) float f32x2;

// intermediates bf16 (xr/hres) and fp8-e4m3 (xl, gather-path) ; all math fp32
__device__ __forceinline__ float bf2f(u16 v) { return __uint_as_float(((u32)v) << 16); }
__device__ __forceinline__ u16 f2bf(float f) {
    u32 x = __float_as_uint(f);
    return (u16)((x + 0x7fffu + ((x >> 16) & 1u)) >> 16);
}

// ---- fp8 via HW converters (V_CVT_PK_*) ----
__device__ __forceinline__ u8 ftofp8_hw(float f) {
    return (u8)((u32)__builtin_amdgcn_cvt_pk_fp8_f32(f, f, 0, false) & 0xffu);
}

// ---- DPP adds on the VALU pipe (ctrl must be a constant -> template) ----
template <int CTRL>
__device__ __forceinline__ float dppadd(float p) {
    return p + __uint_as_float((u32)__builtin_amdgcn_update_dpp(
        0, (int)__float_as_uint(p), CTRL, 0xF, 0xF, true));
}
// full-wave sum, result broadcast (readlane 63)
__device__ __forceinline__ float wave_sum_bcast(float p) {
    p = dppadd<0x111>(p);   // row_shr:1
    p = dppadd<0x112>(p);   // row_shr:2
    p = dppadd<0x114>(p);   // row_shr:4
    p = dppadd<0x118>(p);   // row_shr:8
    p = dppadd<0x142>(p);   // row_bcast15
    p = dppadd<0x143>(p);   // row_bcast31
    return __uint_as_float((u32)__builtin_amdgcn_readlane((int)__float_as_uint(p), 63));
}
// 16-lane (hw-row) sum, broadcast to all 16 lanes of the row.
__device__ __forceinline__ float red16(float p) {
    p = dppadd<0xB1>(p);
    p = dppadd<0x4E>(p);
    p = dppadd<0x141>(p);
    p = dppadd<0x140>(p);
    return p;
}

// ---------------- zero degree array (graph-capture-safe, no memset API) ----------------
__global__ __launch_bounds__(256) void k_zero(int4* __restrict__ deg4) {
    deg4[blockIdx.x * 256 + threadIdx.x] = make_int4(0, 0, 0, 0);
}

// ---------------- prep: edge degree count (4096 blocks) + bf16 n-major weights + MFMA-pack Wq ----------------
__global__ __launch_bounds__(256) void k_prep(
    int* __restrict__ deg, const int* __restrict__ ei,
    const float* __restrict__ Wl, const float* __restrict__ Wr, const float* __restrict__ Wres,
    u16* __restrict__ wt,
    const float* __restrict__ W0, u16* __restrict__ wt0,
    const float* __restrict__ W1, u16* __restrict__ wt1,
    const float* __restrict__ Wq, u16* __restrict__ wqB)
{
    int b = blockIdx.x, t = threadIdx.x;
    if (b < 4096) {
        // degree count (deg zeroed by k_zero)
        int e = b * 256 + t;
        atomicAdd(deg + ei[N_EDGES + e], 1);
        return;
    }
    b -= 4096;
    if (b < 384) {
        int idx = b * 256 + t;                // 0..98303  gat weights [768][128]
        int nn = idx >> 7, k = idx & 127;
        float v;
        if (nn < 256) v = Wl[k * OUTD + nn];
        else if (nn < 512) v = Wr[k * OUTD + (nn - 256)];
        else v = Wres[k * OUTD + (nn - 512)];
        wt[idx] = f2bf(v);
    } else if (b < 432) {
        int idx = (b - 384) * 256 + t;        // 0..12287  W0^T [128][96]
        int nn = idx / 96, k = idx - nn * 96;
        wt0[idx] = f2bf(W0[k * HID + nn]);
    } else if (b < 496) {
        int idx = (b - 432) * 256 + t;        // 0..16383  W1^T [128][128]
        int nn = idx >> 7, k = idx & 127;
        wt1[idx] = f2bf(W1[k * HID + nn]);
    } else {
        // Wq packed into MFMA 16x16x32 B-fragment layout:
        // wqB[((tile*8 + kk)*64 + lane)*8 + j] = Wq[kk*32 + (lane>>4)*8 + j][tile*16 + (lane&15)]
        int idx = (b - 496) * 256 + t;        // 0..8191
        int tile = idx >> 12, rem = idx & 4095;
        int kk = rem >> 9, ln = (rem >> 3) & 63, j = idx & 7;
        int k = kk * 32 + (ln >> 4) * 8 + j;
        int q = tile * 16 + (ln & 15);
        wqB[idx] = (q < N_ACT) ? f2bf(Wq[k * N_ACT + q]) : (u16)0;
    }
}

// ---------------- exclusive scan of degrees -> CSR offsets + mutable cursor copy ----------------
__global__ __launch_bounds__(1024) void k_scan(const int* __restrict__ deg,
                                               int* __restrict__ off, int* __restrict__ cur) {
    __shared__ int part[1024];
    int t = threadIdx.x;
    int base = t * 64;
    const int4* d4 = (const int4*)(deg + base);
    int s = 0;
#pragma unroll
    for (int i = 0; i < 16; i++) { int4 v = d4[i]; s += v.x + v.y + v.z + v.w; }
    part[t] = s;
    __syncthreads();
    for (int o = 1; o < 1024; o <<= 1) {
        int v = (t >= o) ? part[t - o] : 0;
        __syncthreads();
        part[t] += v;
        __syncthreads();
    }
    int run = (t == 0) ? 0 : part[t - 1];
    int4* o4 = (int4*)(off + base);
    int4* c4 = (int4*)(cur + base);
#pragma unroll
    for (int i = 0; i < 16; i++) {
        int4 v = d4[i];
        int4 w;
        w.x = run;
        w.y = run + v.x;
        w.z = w.y + v.y;
        w.w = w.z + v.z;
        run = w.w + v.w;
        o4[i] = w;
        c4[i] = w;
    }
    if (t == 1023) off[N_NODES] = run;
}

// ---------------- fused node pipeline (MFMA): MLP(2x LN) -> xl8/xr/hres, + CSR scatter fold ----------------
// blocks [0,1024): MLP, 4 waves x 16 nodes (r1 measured-good structure);
// blocks [1024,5120): edge scatter via atomic cursor (overlaps MLP compute; replaces k_scatter).
__global__ __launch_bounds__(256, 4) void k_fused(
    const float* __restrict__ in,
    const u16* __restrict__ wt0, const u16* __restrict__ wt1, const u16* __restrict__ wt,
    const float* __restrict__ b0, const float* __restrict__ g0, const float* __restrict__ be0,
    const float* __restrict__ b1, const float* __restrict__ g1, const float* __restrict__ be1,
    const float* __restrict__ bl, const float* __restrict__ br, const float* __restrict__ gbias,
    const int* __restrict__ ei, const float* __restrict__ ea,
    int* __restrict__ cur, int4* __restrict__ erec,
    u8* __restrict__ xl8, u16* __restrict__ xr, u16* __restrict__ hres)
{
    if (blockIdx.x >= 1024) {
        // CSR scatter: one edge per thread; cursor atomic gives the slot
        int e = (blockIdx.x - 1024) * 256 + threadIdx.x;
        int src = ei[e];
        int dst = ei[N_EDGES + e];
        float a0 = ea[e * 3 + 0];
        float a1 = ea[e * 3 + 1];
        float a2 = ea[e * 3 + 2];
        int pos = atomicAdd(cur + dst, 1);
        erec[pos] = make_int4(src, __float_as_int(a0), __float_as_int(a1), __float_as_int(a2));
        return;
    }
    int wid = threadIdx.x >> 6, lane = threadIdx.x & 63;
    int l15 = lane & 15, quad = lane >> 4;
    int m0 = (blockIdx.x * 4 + wid) * 16;

    __shared__ u16 xbuf[4][16][136];   // per-wave x-strip (bf16)

    f32x4 acc[8];

    // ===== layer 0: [16 x 96] @ W0 -> [16 x 128], relu + LN =====
#pragma unroll
    for (int t = 0; t < 8; t++) acc[t] = {0.f, 0.f, 0.f, 0.f};
#pragma unroll
    for (int kk = 0; kk < 3; kk++) {
        const float* ap = in + (long)(m0 + l15) * IN_DIM + kk * 32 + quad * 8;
        float4 fa = *(const float4*)(ap);
        float4 fb = *(const float4*)(ap + 4);
        bf16x8 af;
        af[0] = (short)f2bf(fa.x); af[1] = (short)f2bf(fa.y);
        af[2] = (short)f2bf(fa.z); af[3] = (short)f2bf(fa.w);
        af[4] = (short)f2bf(fb.x); af[5] = (short)f2bf(fb.y);
        af[6] = (short)f2bf(fb.z); af[7] = (short)f2bf(fb.w);
#pragma unroll
        for (int t = 0; t < 8; t++) {
            bf16x8 bf = *(const bf16x8*)(wt0 + (t * 16 + l15) * IN_DIM + kk * 32 + quad * 8);
            acc[t] = __builtin_amdgcn_mfma_f32_16x16x32_bf16(af, bf, acc[t], 0, 0, 0);
        }
    }
    {
        float bv[8], gv[8], bev[8];
#pragma unroll
        for (int t = 0; t < 8; t++) {
            int col = t * 16 + l15;
            bv[t] = b0[col]; gv[t] = g0[col]; bev[t] = be0[col];
        }
#pragma unroll
        for (int g = 0; g < 4; g++) {
            float s_ = 0.f, q_ = 0.f;
#pragma unroll
            for (int t = 0; t < 8; t++) {
                float x = fmaxf(acc[t][g] + bv[t], 0.f);
                acc[t][g] = x;
                s_ += x;
                q_ = fmaf(x, x, q_);
            }
            s_ = red16(s_);
            q_ = red16(q_);
            float mu = s_ * (1.f / HID);
            float var = q_ * (1.f / HID) - mu * mu;
            float rs = rsqrtf(fmaxf(var, 0.f) + 1e-5f);
#pragma unroll
            for (int t = 0; t < 8; t++) {
                float y = (acc[t][g] - mu) * rs * gv[t] + bev[t];
                xbuf[wid][quad * 4 + g][t * 16 + l15] = f2bf(y);
            }
        }
    }

    // ===== layer 1: [16 x 128] @ W1 -> [16 x 128], relu + LN =====
#pragma unroll
    for (int t = 0; t < 8; t++) acc[t] = {0.f, 0.f, 0.f, 0.f};
#pragma unroll
    for (int kk = 0; kk < 4; kk++) {
        bf16x8 af = *(const bf16x8*)(&xbuf[wid][l15][kk * 32 + quad * 8]);
#pragma unroll
        for (int t = 0; t < 8; t++) {
            bf16x8 bf = *(const bf16x8*)(wt1 + (t * 16 + l15) * HID + kk * 32 + quad * 8);
            acc[t] = __builtin_amdgcn_mfma_f32_16x16x32_bf16(af, bf, acc[t], 0, 0, 0);
        }
    }
    {
        float bv[8], gv[8], bev[8];
#pragma unroll
        for (int t = 0; t < 8; t++) {
            int col = t * 16 + l15;
            bv[t] = b1[col]; gv[t] = g1[col]; bev[t] = be1[col];
        }
#pragma unroll
        for (int g = 0; g < 4; g++) {
            float s_ = 0.f, q_ = 0.f;
#pragma unroll
            for (int t = 0; t < 8; t++) {
                float x = fmaxf(acc[t][g] + bv[t], 0.f);
                acc[t][g] = x;
                s_ += x;
                q_ = fmaf(x, x, q_);
            }
            s_ = red16(s_);
            q_ = red16(q_);
            float mu = s_ * (1.f / HID);
            float var = q_ * (1.f / HID) - mu * mu;
            float rs = rsqrtf(fmaxf(var, 0.f) + 1e-5f);
#pragma unroll
            for (int t = 0; t < 8; t++) {
                float y = (acc[t][g] - mu) * rs * gv[t] + bev[t];
                xbuf[wid][quad * 4 + g][t * 16 + l15] = f2bf(y);
            }
        }
    }

    // ===== projections: x1 @ {Wl|Wr|Wres} + bias -> xl8(fp8 HW)/xr/hres =====
    for (int nT = 0; nT < 3; nT++) {
        f32x4 pacc[16];
#pragma unroll
        for (int t = 0; t < 16; t++) pacc[t] = {0.f, 0.f, 0.f, 0.f};
#pragma unroll
        for (int kk = 0; kk < 4; kk++) {
            bf16x8 af = *(const bf16x8*)(&xbuf[wid][l15][kk * 32 + quad * 8]);
#pragma unroll
            for (int t = 0; t < 16; t++) {
                bf16x8 bf = *(const bf16x8*)(wt + (long)(nT * 256 + t * 16 + l15) * HID + kk * 32 + quad * 8);
                pacc[t] = __builtin_amdgcn_mfma_f32_16x16x32_bf16(af, bf, pacc[t], 0, 0, 0);
            }
        }
        if (nT == 0) {
#pragma unroll
            for (int t = 0; t < 16; t++) {
                int col = t * 16 + l15;
                float bvv = bl[col];
#pragma unroll
                for (int g = 0; g < 4; g++) {
                    xl8[(long)(m0 + quad * 4 + g) * OUTD + col] = ftofp8_hw(pacc[t][g] + bvv);
                }
            }
        } else {
            const float* bias = (nT == 1) ? br : gbias;
            u16* dst = (nT == 1) ? xr : hres;
#pragma unroll
            for (int t = 0; t < 16; t++) {
                int col = t * 16 + l15;
                float bvv = bias[col];
#pragma unroll
                for (int g = 0; g < 4; g++) {
                    dst[(long)(m0 + quad * 4 + g) * OUTD + col] = f2bf(pacc[t][g] + bvv);
                }
            }
        }
    }
}

// ---------------- fused aggregation (r1 version, measured-good): 4 edges/iter pipelined, ----------------
// packed-f32 math, DPP wave-sum, fp8 HW pair-decode, MFMA head matmul.
__global__ __launch_bounds__(256, 4) void k_agg_fused(
    const int* __restrict__ off, const int4* __restrict__ erec,
    const u8* __restrict__ xl8, const u16* __restrict__ xr, const u16* __restrict__ hres,
    const float* __restrict__ We, const float* __restrict__ att,
    const float* __restrict__ g2, const float* __restrict__ be2,
    const u16* __restrict__ wqB, const float* __restrict__ bq,
    float* __restrict__ out)
{
    int wid = threadIdx.x >> 6, lane = threadIdx.x & 63;
    int n = blockIdx.x * 4 + wid;
    int j0 = lane * 4;
    __shared__ __align__(16) u16 ylds[4][256];

    const float LOG2E = 1.44269504088896f;

    float4 w0 = *(const float4*)(We + j0);
    float4 w1 = *(const float4*)(We + OUTD + j0);
    float4 w2 = *(const float4*)(We + 2 * OUTD + j0);
    float4 avf = *(const float4*)(att + j0);
    f32x2 w0_01 = {w0.x, w0.y}, w0_23 = {w0.z, w0.w};
    f32x2 w1_01 = {w1.x, w1.y}, w1_23 = {w1.z, w1.w};
    f32x2 w2_01 = {w2.x, w2.y}, w2_23 = {w2.z, w2.w};
    // fold log2(e) into att: softmax exp becomes a single native v_exp_f32 (2^x)
    f32x2 av01 = {avf.x * LOG2E, avf.y * LOG2E};
    f32x2 av23 = {avf.z * LOG2E, avf.w * LOG2E};

    ushort4 xrv = *(const ushort4*)(xr + (long)n * OUTD + j0);
    f32x2 xr01 = {bf2f(xrv.x), bf2f(xrv.y)};
    f32x2 xr23 = {bf2f(xrv.z), bf2f(xrv.w)};

    int beg = off[n], end = off[n + 1];

    float s = 0.f;
    f32x2 a01 = {0.f, 0.f}, a23 = {0.f, 0.f};

    // per-edge logit in log2 domain; also returns decoded fp8 pairs for reuse
    auto logit = [&](const int4& r, u32 v, f32x2& d0, f32x2& d1) -> float {
        d0 = __builtin_amdgcn_cvt_pk_f32_fp8((int)v, false);
        d1 = __builtin_amdgcn_cvt_pk_f32_fp8((int)v, true);
        f32x2 ea0 = {__int_as_float(r.y), __int_as_float(r.y)};
        f32x2 ea1 = {__int_as_float(r.z), __int_as_float(r.z)};
        f32x2 ea2 = {__int_as_float(r.w), __int_as_float(r.w)};
        f32x2 t01 = d0 + xr01;
        t01 = __builtin_elementwise_fma(ea0, w0_01, t01);
        t01 = __builtin_elementwise_fma(ea1, w1_01, t01);
        t01 = __builtin_elementwise_fma(ea2, w2_01, t01);
        f32x2 t23 = d1 + xr23;
        t23 = __builtin_elementwise_fma(ea0, w0_23, t23);
        t23 = __builtin_elementwise_fma(ea1, w1_23, t23);
        t23 = __builtin_elementwise_fma(ea2, w2_23, t23);
        f32x2 l01 = __builtin_elementwise_max(t01, 0.2f * t01);
        f32x2 l23 = __builtin_elementwise_max(t23, 0.2f * t23);
        f32x2 pv = l01 * av01;
        pv = __builtin_elementwise_fma(l23, av23, pv);
        return pv[0] + pv[1];
    };

    if (beg < end) {
        int4 r0, r1, r2, r3;
        u32 v0, v1, v2, v3;
        {
            int i1 = min(beg + 1, end - 1), i2 = min(beg + 2, end - 1), i3 = min(beg + 3, end - 1);
            r0 = erec[beg]; r1 = erec[i1]; r2 = erec[i2]; r3 = erec[i3];
            v0 = *(const u32*)(xl8 + (long)r0.x * OUTD + j0);
            v1 = *(const u32*)(xl8 + (long)r1.x * OUTD + j0);
            v2 = *(const u32*)(xl8 + (long)r2.x * OUTD + j0);
            v3 = *(const u32*)(xl8 + (long)r3.x * OUTD + j0);
        }
#pragma unroll 1
        for (int i = beg; i < end; i += 4) {
            // prefetch next iteration (clamped; harmless dup reads on tail)
            int nb = i + 4;
            int p0i = min(nb, end - 1), p1i = min(nb + 1, end - 1);
            int p2i = min(nb + 2, end - 1), p3i = min(nb + 3, end - 1);
            int4 nr0 = erec[p0i], nr1 = erec[p1i], nr2 = erec[p2i], nr3 = erec[p3i];
            u32 nv0 = *(const u32*)(xl8 + (long)nr0.x * OUTD + j0);
            u32 nv1 = *(const u32*)(xl8 + (long)nr1.x * OUTD + j0);
            u32 nv2 = *(const u32*)(xl8 + (long)nr2.x * OUTD + j0);
            u32 nv3 = *(const u32*)(xl8 + (long)nr3.x * OUTD + j0);

            f32x2 d00, d01, d10, d11, d20, d21, d30, d31;
            float p0 = logit(r0, v0, d00, d01);
            float p1 = logit(r1, v1, d10, d11);
            float p2 = logit(r2, v2, d20, d21);
            float p3 = logit(r3, v3, d30, d31);

            p0 = wave_sum_bcast(p0);
            p1 = wave_sum_bcast(p1);
            p2 = wave_sum_bcast(p2);
            p3 = wave_sum_bcast(p3);
            if (i + 1 >= end) p1 = -1.0e30f;   // exp2 -> 0
            if (i + 2 >= end) p2 = -1.0e30f;
            if (i + 3 >= end) p3 = -1.0e30f;

            float e0 = __builtin_amdgcn_exp2f(p0);
            float e1 = __builtin_amdgcn_exp2f(p1);
            float e2 = __builtin_amdgcn_exp2f(p2);
            float e3 = __builtin_amdgcn_exp2f(p3);
            s += (e0 + e1) + (e2 + e3);

            f32x2 e0v = {e0, e0}, e1v = {e1, e1}, e2v = {e2, e2}, e3v = {e3, e3};
            a01 = __builtin_elementwise_fma(e0v, d00, a01);
            a23 = __builtin_elementwise_fma(e0v, d01, a23);
            a01 = __builtin_elementwise_fma(e1v, d10, a01);
            a23 = __builtin_elementwise_fma(e1v, d11, a23);
            a01 = __builtin_elementwise_fma(e2v, d20, a01);
            a23 = __builtin_elementwise_fma(e2v, d21, a23);
            a01 = __builtin_elementwise_fma(e3v, d30, a01);
            a23 = __builtin_elementwise_fma(e3v, d31, a23);

            r0 = nr0; r1 = nr1; r2 = nr2; r3 = nr3;
            v0 = nv0; v1 = nv1; v2 = nv2; v3 = nv3;
        }
    }

    float inv = (end > beg) ? 1.f / s : 0.f;

    ushort4 hv = *(const ushort4*)(hres + (long)n * OUTD + j0);
    float h0 = fmaxf(fmaf(a01[0], inv, bf2f(hv.x)), 0.f);
    float h1 = fmaxf(fmaf(a01[1], inv, bf2f(hv.y)), 0.f);
    float h2 = fmaxf(fmaf(a23[0], inv, bf2f(hv.z)), 0.f);
    float h3 = fmaxf(fmaf(a23[1], inv, bf2f(hv.w)), 0.f);

    float sum = h0 + h1 + h2 + h3;
    float sq = h0 * h0 + h1 * h1 + h2 * h2 + h3 * h3;
    sum = wave_sum_bcast(sum);
    sq = wave_sum_bcast(sq);
    float mu = sum * (1.f / OUTD);
    float var = sq * (1.f / OUTD) - mu * mu;
    float rs = rsqrtf(fmaxf(var, 0.f) + 1e-5f);

    float4 gv = *(const float4*)(g2 + j0);
    float4 bv = *(const float4*)(be2 + j0);
    ushort4 yy;
    yy.x = f2bf((h0 - mu) * rs * gv.x + bv.x);
    yy.y = f2bf((h1 - mu) * rs * gv.y + bv.y);
    yy.z = f2bf((h2 - mu) * rs * gv.z + bv.z);
    yy.w = f2bf((h3 - mu) * rs * gv.w + bv.w);
    *(ushort4*)(&ylds[wid][j0]) = yy;
    __syncthreads();

    // ===== head: q = y @ Wq + bq via one MFMA pass (wave0: cols 0-15, wave1: cols 16-19) =====
    if (wid < 2) {
        int row = lane & 15, qd = lane >> 4;
        const u16* ab = &ylds[row & 3][qd * 8];   // rows 4-15 duplicate rows 0-3 (unused C rows)
        f32x4 cacc = {0.f, 0.f, 0.f, 0.f};
#pragma unroll
        for (int kk = 0; kk < 8; kk++) {
            bf16x8 afrag = *(const bf16x8*)(ab + kk * 32);
            bf16x8 bfrag = *(const bf16x8*)(wqB + ((((wid << 3) + kk) << 6) + lane) * 8);
            cacc = __builtin_amdgcn_mfma_f32_16x16x32_bf16(afrag, bfrag, cacc, 0, 0, 0);
        }
        // C layout: col=lane&15, row=(lane>>4)*4+g; lanes 0-15 hold rows(=nodes) 0-3 in g
        if (lane < 16) {
            int q = wid * 16 + lane;
            if (q < N_ACT) {
                float bqv = bq[q];
                long nb = (long)blockIdx.x * 4;
#pragma unroll
                for (int g = 0; g < 4; g++)
                    out[(nb + g) * N_ACT + q] = cacc[g] + bqv;
            }
        }
    }
}

extern "C" void kernel_launch(void* const* d_in, const int* in_sizes, int n_in,
                              void* d_out, int out_size, void* d_ws, size_t ws_size,
                              hipStream_t stream) {
    (void)in_sizes; (void)n_in; (void)out_size; (void)ws_size;
    const float* inp  = (const float*)d_in[0];
    const int*   ei   = (const int*)d_in[1];
    const float* ea   = (const float*)d_in[2];
    const float* W0   = (const float*)d_in[3];
    const float* b0   = (const float*)d_in[4];
    const float* g0   = (const float*)d_in[5];
    const float* be0  = (const float*)d_in[6];
    const float* W1   = (const float*)d_in[7];
    const float* b1   = (const float*)d_in[8];
    const float* g1   = (const float*)d_in[9];
    const float* be1  = (const float*)d_in[10];
    const float* Wl   = (const float*)d_in[11];
    const float* bl   = (const float*)d_in[12];
    const float* Wr   = (const float*)d_in[13];
    const float* br   = (const float*)d_in[14];
    const float* We   = (const float*)d_in[15];
    const float* att  = (const float*)d_in[16];
    const float* Wres = (const float*)d_in[17];
    const float* gbias= (const float*)d_in[18];
    const float* g2   = (const float*)d_in[19];
    const float* be2  = (const float*)d_in[20];
    const float* Wq   = (const float*)d_in[21];
    const float* bq   = (const float*)d_in[22];
    float* out = (float*)d_out;

    char* ws = (char*)d_ws;
    size_t o = 0;
    auto alloc = [&](size_t bytes) -> void* {
        void* p = ws + o;
        o += (bytes + 255) & ~(size_t)255;
        return p;
    };
    u8*    xl8    = (u8*)   alloc((size_t)N_NODES * OUTD);        // 16 MiB (fp8 e4m3)
    u16*   xr     = (u16*)  alloc((size_t)N_NODES * OUTD * 2);    // 32 MiB
    u16*   hres   = (u16*)  alloc((size_t)N_NODES * OUTD * 2);    // 32 MiB
    int*   deg    = (int*)  alloc((size_t)N_NODES * 4);           // 256 KiB
    int*   off    = (int*)  alloc((size_t)(N_NODES + 1) * 4);
    int*   cur    = (int*)  alloc((size_t)N_NODES * 4);           // mutable CSR cursor
    int4*  erec   = (int4*) alloc((size_t)N_EDGES * 16);          // 16 MiB
    u16*   wt     = (u16*)  alloc((size_t)768 * HID * 2);         // 192 KiB  gat [768][128]
    u16*   wt0    = (u16*)  alloc((size_t)HID * IN_DIM * 2);      // 24 KiB   W0^T [128][96]
    u16*   wt1    = (u16*)  alloc((size_t)HID * HID * 2);         // 32 KiB   W1^T [128][128]
    u16*   wqB    = (u16*)  alloc((size_t)2 * 8 * 64 * 8 * 2);    // 16 KiB   Wq MFMA B-frags

    k_zero<<<64, 256, 0, stream>>>((int4*)deg);
    k_prep<<<4096 + 528, 256, 0, stream>>>(deg, ei, Wl, Wr, Wres, wt, W0, wt0, W1, wt1, Wq, wqB);
    k_scan<<<1, 1024, 0, stream>>>(deg, off, cur);
    k_fused<<<1024 + N_EDGES / 256, 256, 0, stream>>>(inp, wt0, wt1, wt,
        b0, g0, be0, b1, g1, be1, bl, br, gbias, ei, ea, cur, erec, xl8, xr, hres);
    k_agg_fused<<<N_NODES / 4, 256, 0, stream>>>(off, erec, xl8, xr, hres, We, att, g2, be2, wqB, bq, out);
}

// Round 5
// 411.896 us; speedup vs baseline: 1.3926x; 1.1974x over previous
//
#include <hip/hip_runtime.h>
#include <hip/hip_bf16.h>

#define N_NODES 65536
#define N_EDGES 1048576
#define IN_DIM 96
#define HID 128
#define OUTD 256
#define N_ACT 20

typedef unsigned short u16;
typedef unsigned char u8;
typedef unsigned int u32;
typedef __attribute__((ext_vector_type(8))) short bf16x8;
typedef __attribute__((ext_vector_type(4))) float f32x4;
typedef __attribute__((ext_vector_type(2))) float f32x2;

// intermediates bf16 (xr/hres) and fp8-e4m3 (xl, gather-path) ; all math fp32
__device__ __forceinline__ float bf2f(u16 v) { return __uint_as_float(((u32)v) << 16); }
__device__ __forceinline__ u16 f2bf(float f) {
    u32 x = __float_as_uint(f);
    return (u16)((x + 0x7fffu + ((x >> 16) & 1u)) >> 16);
}

// ---- fp8 via HW converters (V_CVT_PK_*) ----
__device__ __forceinline__ u8 ftofp8_hw(float f) {
    return (u8)((u32)__builtin_amdgcn_cvt_pk_fp8_f32(f, f, 0, false) & 0xffu);
}

// ---- DPP adds on the VALU pipe (ctrl must be a constant -> template) ----
template <int CTRL>
__device__ __forceinline__ float dppadd(float p) {
    return p + __uint_as_float((u32)__builtin_amdgcn_update_dpp(
        0, (int)__float_as_uint(p), CTRL, 0xF, 0xF, true));
}
// full-wave sum, result broadcast (readlane 63)
__device__ __forceinline__ float wave_sum_bcast(float p) {
    p = dppadd<0x111>(p);   // row_shr:1
    p = dppadd<0x112>(p);   // row_shr:2
    p = dppadd<0x114>(p);   // row_shr:4
    p = dppadd<0x118>(p);   // row_shr:8
    p = dppadd<0x142>(p);   // row_bcast15
    p = dppadd<0x143>(p);   // row_bcast31
    return __uint_as_float((u32)__builtin_amdgcn_readlane((int)__float_as_uint(p), 63));
}
// 16-lane (hw-row) sum, broadcast to all 16 lanes of the row.
__device__ __forceinline__ float red16(float p) {
    p = dppadd<0xB1>(p);
    p = dppadd<0x4E>(p);
    p = dppadd<0x141>(p);
    p = dppadd<0x140>(p);
    return p;
}

// ---------------- prep: zero deg + bf16 n-major weights + MFMA-pack Wq ----------------
__global__ __launch_bounds__(256) void k_prep(
    int* __restrict__ deg,
    const float* __restrict__ Wl, const float* __restrict__ Wr, const float* __restrict__ Wres,
    u16* __restrict__ wt,
    const float* __restrict__ W0, u16* __restrict__ wt0,
    const float* __restrict__ W1, u16* __restrict__ wt1,
    const float* __restrict__ Wq, u16* __restrict__ wqB)
{
    int b = blockIdx.x, t = threadIdx.x;
    if (b < 256) {
        deg[b * 256 + t] = 0;
    } else if (b < 640) {
        int idx = (b - 256) * 256 + t;        // 0..98303  gat weights [768][128]
        int nn = idx >> 7, k = idx & 127;
        float v;
        if (nn < 256) v = Wl[k * OUTD + nn];
        else if (nn < 512) v = Wr[k * OUTD + (nn - 256)];
        else v = Wres[k * OUTD + (nn - 512)];
        wt[idx] = f2bf(v);
    } else if (b < 688) {
        int idx = (b - 640) * 256 + t;        // 0..12287  W0^T [128][96]
        int nn = idx / 96, k = idx - nn * 96;
        wt0[idx] = f2bf(W0[k * HID + nn]);
    } else if (b < 752) {
        int idx = (b - 688) * 256 + t;        // 0..16383  W1^T [128][128]
        int nn = idx >> 7, k = idx & 127;
        wt1[idx] = f2bf(W1[k * HID + nn]);
    } else {
        // Wq packed into MFMA 16x16x32 B-fragment layout:
        // wqB[((tile*8 + kk)*64 + lane)*8 + j] = Wq[kk*32 + (lane>>4)*8 + j][tile*16 + (lane&15)]
        int idx = (b - 752) * 256 + t;        // 0..8191
        int tile = idx >> 12, rem = idx & 4095;
        int kk = rem >> 9, ln = (rem >> 3) & 63, j = idx & 7;
        int k = kk * 32 + (ln >> 4) * 8 + j;
        int q = tile * 16 + (ln & 15);
        wqB[idx] = (q < N_ACT) ? f2bf(Wq[k * N_ACT + q]) : (u16)0;
    }
}

// ---------------- exclusive scan of degrees -> CSR offsets (int4-vectorized) ----------------
__global__ __launch_bounds__(1024) void k_scan(const int* __restrict__ deg, int* __restrict__ off) {
    __shared__ int part[1024];
    int t = threadIdx.x;
    int base = t * 64;
    const int4* d4 = (const int4*)(deg + base);
    int s = 0;
#pragma unroll
    for (int i = 0; i < 16; i++) { int4 v = d4[i]; s += v.x + v.y + v.z + v.w; }
    part[t] = s;
    __syncthreads();
    for (int o = 1; o < 1024; o <<= 1) {
        int v = (t >= o) ? part[t - o] : 0;
        __syncthreads();
        part[t] += v;
        __syncthreads();
    }
    int run = (t == 0) ? 0 : part[t - 1];
    int4* o4 = (int4*)(off + base);
#pragma unroll
    for (int i = 0; i < 16; i++) {
        int4 v = d4[i];
        int4 w;
        w.x = run;
        w.y = run + v.x;
        w.z = w.y + v.y;
        w.w = w.z + v.z;
        run = w.w + v.w;
        o4[i] = w;
    }
    if (t == 1023) off[N_NODES] = run;
}

// ---------------- scatter edge records into CSR order (atomic-free: rank from deg pass) ----------------
__global__ __launch_bounds__(256) void k_scatter(
    const int* __restrict__ ei, const float* __restrict__ ea,
    const int* __restrict__ off, const int* __restrict__ rank,
    int4* __restrict__ erec)
{
    int e = blockIdx.x * 256 + threadIdx.x;
    int src = ei[e];
    int dst = ei[N_EDGES + e];
    float a0 = ea[e * 3 + 0];
    float a1 = ea[e * 3 + 1];
    float a2 = ea[e * 3 + 2];
    int pos = off[dst] + rank[e];
    erec[pos] = make_int4(src, __float_as_int(a0), __float_as_int(a1), __float_as_int(a2));
}

// ---------------- fused node pipeline (MFMA): MLP(2x LN) -> xl8/xr/hres, + deg/rank fold ----------------
// blocks [0,512): MLP, 4 waves x 32 nodes (2 M-tiles/wave: every weight fragment feeds 2 MFMAs);
// blocks [512,4608): degree count + edge rank (overlaps MLP, r1 measured-good).
__global__ __launch_bounds__(256, 4) void k_fused(
    const float* __restrict__ in,
    const u16* __restrict__ wt0, const u16* __restrict__ wt1, const u16* __restrict__ wt,
    const float* __restrict__ b0, const float* __restrict__ g0, const float* __restrict__ be0,
    const float* __restrict__ b1, const float* __restrict__ g1, const float* __restrict__ be1,
    const float* __restrict__ bl, const float* __restrict__ br, const float* __restrict__ gbias,
    const int* __restrict__ ei, int* __restrict__ deg, int* __restrict__ rank,
    u8* __restrict__ xl8, u16* __restrict__ xr, u16* __restrict__ hres)
{
    if (blockIdx.x >= 512) {
        int e = (blockIdx.x - 512) * 256 + threadIdx.x;
        rank[e] = atomicAdd(deg + ei[N_EDGES + e], 1);   // rank = within-node slot
        return;
    }
    int wid = threadIdx.x >> 6, lane = threadIdx.x & 63;
    int l15 = lane & 15, quad = lane >> 4;
    int m0 = (blockIdx.x * 4 + wid) * 32;

    __shared__ u16 xbuf[4][32][136];   // per-wave x-strip (bf16), 2 M-tiles

    f32x4 acc[2][8];

    // ===== layer 0: [32 x 96] @ W0 -> [32 x 128], relu + LN =====
#pragma unroll
    for (int mt = 0; mt < 2; mt++)
#pragma unroll
        for (int t = 0; t < 8; t++) acc[mt][t] = {0.f, 0.f, 0.f, 0.f};
#pragma unroll
    for (int kk = 0; kk < 3; kk++) {
        bf16x8 af[2];
#pragma unroll
        for (int mt = 0; mt < 2; mt++) {
            const float* ap = in + (long)(m0 + mt * 16 + l15) * IN_DIM + kk * 32 + quad * 8;
            float4 fa = *(const float4*)(ap);
            float4 fb = *(const float4*)(ap + 4);
            af[mt][0] = (short)f2bf(fa.x); af[mt][1] = (short)f2bf(fa.y);
            af[mt][2] = (short)f2bf(fa.z); af[mt][3] = (short)f2bf(fa.w);
            af[mt][4] = (short)f2bf(fb.x); af[mt][5] = (short)f2bf(fb.y);
            af[mt][6] = (short)f2bf(fb.z); af[mt][7] = (short)f2bf(fb.w);
        }
#pragma unroll
        for (int t = 0; t < 8; t++) {
            bf16x8 bf = *(const bf16x8*)(wt0 + (t * 16 + l15) * IN_DIM + kk * 32 + quad * 8);
            acc[0][t] = __builtin_amdgcn_mfma_f32_16x16x32_bf16(af[0], bf, acc[0][t], 0, 0, 0);
            acc[1][t] = __builtin_amdgcn_mfma_f32_16x16x32_bf16(af[1], bf, acc[1][t], 0, 0, 0);
        }
    }
    {
        float bv[8], gv[8], bev[8];
#pragma unroll
        for (int t = 0; t < 8; t++) {
            int col = t * 16 + l15;
            bv[t] = b0[col]; gv[t] = g0[col]; bev[t] = be0[col];
        }
#pragma unroll
        for (int mt = 0; mt < 2; mt++) {
#pragma unroll
            for (int g = 0; g < 4; g++) {
                float s_ = 0.f, q_ = 0.f;
#pragma unroll
                for (int t = 0; t < 8; t++) {
                    float x = fmaxf(acc[mt][t][g] + bv[t], 0.f);
                    acc[mt][t][g] = x;
                    s_ += x;
                    q_ = fmaf(x, x, q_);
                }
                s_ = red16(s_);
                q_ = red16(q_);
                float mu = s_ * (1.f / HID);
                float var = q_ * (1.f / HID) - mu * mu;
                float rs = rsqrtf(fmaxf(var, 0.f) + 1e-5f);
#pragma unroll
                for (int t = 0; t < 8; t++) {
                    float y = (acc[mt][t][g] - mu) * rs * gv[t] + bev[t];
                    xbuf[wid][mt * 16 + quad * 4 + g][t * 16 + l15] = f2bf(y);
                }
            }
        }
    }

    // ===== layer 1: [32 x 128] @ W1 -> [32 x 128], relu + LN =====
#pragma unroll
    for (int mt = 0; mt < 2; mt++)
#pragma unroll
        for (int t = 0; t < 8; t++) acc[mt][t] = {0.f, 0.f, 0.f, 0.f};
#pragma unroll
    for (int kk = 0; kk < 4; kk++) {
        bf16x8 af0 = *(const bf16x8*)(&xbuf[wid][l15][kk * 32 + quad * 8]);
        bf16x8 af1 = *(const bf16x8*)(&xbuf[wid][16 + l15][kk * 32 + quad * 8]);
#pragma unroll
        for (int t = 0; t < 8; t++) {
            bf16x8 bf = *(const bf16x8*)(wt1 + (t * 16 + l15) * HID + kk * 32 + quad * 8);
            acc[0][t] = __builtin_amdgcn_mfma_f32_16x16x32_bf16(af0, bf, acc[0][t], 0, 0, 0);
            acc[1][t] = __builtin_amdgcn_mfma_f32_16x16x32_bf16(af1, bf, acc[1][t], 0, 0, 0);
        }
    }
    {
        float bv[8], gv[8], bev[8];
#pragma unroll
        for (int t = 0; t < 8; t++) {
            int col = t * 16 + l15;
            bv[t] = b1[col]; gv[t] = g1[col]; bev[t] = be1[col];
        }
#pragma unroll
        for (int mt = 0; mt < 2; mt++) {
#pragma unroll
            for (int g = 0; g < 4; g++) {
                float s_ = 0.f, q_ = 0.f;
#pragma unroll
                for (int t = 0; t < 8; t++) {
                    float x = fmaxf(acc[mt][t][g] + bv[t], 0.f);
                    acc[mt][t][g] = x;
                    s_ += x;
                    q_ = fmaf(x, x, q_);
                }
                s_ = red16(s_);
                q_ = red16(q_);
                float mu = s_ * (1.f / HID);
                float var = q_ * (1.f / HID) - mu * mu;
                float rs = rsqrtf(fmaxf(var, 0.f) + 1e-5f);
#pragma unroll
                for (int t = 0; t < 8; t++) {
                    float y = (acc[mt][t][g] - mu) * rs * gv[t] + bev[t];
                    xbuf[wid][mt * 16 + quad * 4 + g][t * 16 + l15] = f2bf(y);
                }
            }
        }
    }

    // ===== projections: x1 @ {Wl|Wr|Wres} + bias -> xl8(fp8 HW)/xr/hres =====
    // col-halves keep regs bounded (pacc[2][8]); every weight fragment feeds 2 MFMAs.
    for (int nT = 0; nT < 3; nT++) {
        for (int h = 0; h < 2; h++) {
            f32x4 pacc[2][8];
#pragma unroll
            for (int mt = 0; mt < 2; mt++)
#pragma unroll
                for (int t = 0; t < 8; t++) pacc[mt][t] = {0.f, 0.f, 0.f, 0.f};
#pragma unroll
            for (int kk = 0; kk < 4; kk++) {
                bf16x8 af0 = *(const bf16x8*)(&xbuf[wid][l15][kk * 32 + quad * 8]);
                bf16x8 af1 = *(const bf16x8*)(&xbuf[wid][16 + l15][kk * 32 + quad * 8]);
#pragma unroll
                for (int t = 0; t < 8; t++) {
                    bf16x8 bf = *(const bf16x8*)(wt + (long)(nT * 256 + h * 128 + t * 16 + l15) * HID + kk * 32 + quad * 8);
                    pacc[0][t] = __builtin_amdgcn_mfma_f32_16x16x32_bf16(af0, bf, pacc[0][t], 0, 0, 0);
                    pacc[1][t] = __builtin_amdgcn_mfma_f32_16x16x32_bf16(af1, bf, pacc[1][t], 0, 0, 0);
                }
            }
            if (nT == 0) {
#pragma unroll
                for (int t = 0; t < 8; t++) {
                    int col = h * 128 + t * 16 + l15;
                    float bvv = bl[col];
#pragma unroll
                    for (int mt = 0; mt < 2; mt++)
#pragma unroll
                        for (int g = 0; g < 4; g++) {
                            xl8[(long)(m0 + mt * 16 + quad * 4 + g) * OUTD + col] = ftofp8_hw(pacc[mt][t][g] + bvv);
                        }
                }
            } else {
                const float* bias = (nT == 1) ? br : gbias;
                u16* dst = (nT == 1) ? xr : hres;
#pragma unroll
                for (int t = 0; t < 8; t++) {
                    int col = h * 128 + t * 16 + l15;
                    float bvv = bias[col];
#pragma unroll
                    for (int mt = 0; mt < 2; mt++)
#pragma unroll
                        for (int g = 0; g < 4; g++) {
                            dst[(long)(m0 + mt * 16 + quad * 4 + g) * OUTD + col] = f2bf(pacc[mt][t][g] + bvv);
                        }
                }
            }
        }
    }
}

// ---------------- fused aggregation (r1 version, measured-good): 4 edges/iter pipelined, ----------------
// packed-f32 math, DPP wave-sum, fp8 HW pair-decode, MFMA head matmul.
__global__ __launch_bounds__(256, 4) void k_agg_fused(
    const int* __restrict__ off, const int4* __restrict__ erec,
    const u8* __restrict__ xl8, const u16* __restrict__ xr, const u16* __restrict__ hres,
    const float* __restrict__ We, const float* __restrict__ att,
    const float* __restrict__ g2, const float* __restrict__ be2,
    const u16* __restrict__ wqB, const float* __restrict__ bq,
    float* __restrict__ out)
{
    int wid = threadIdx.x >> 6, lane = threadIdx.x & 63;
    int n = blockIdx.x * 4 + wid;
    int j0 = lane * 4;
    __shared__ __align__(16) u16 ylds[4][256];

    const float LOG2E = 1.44269504088896f;

    float4 w0 = *(const float4*)(We + j0);
    float4 w1 = *(const float4*)(We + OUTD + j0);
    float4 w2 = *(const float4*)(We + 2 * OUTD + j0);
    float4 avf = *(const float4*)(att + j0);
    f32x2 w0_01 = {w0.x, w0.y}, w0_23 = {w0.z, w0.w};
    f32x2 w1_01 = {w1.x, w1.y}, w1_23 = {w1.z, w1.w};
    f32x2 w2_01 = {w2.x, w2.y}, w2_23 = {w2.z, w2.w};
    // fold log2(e) into att: softmax exp becomes a single native v_exp_f32 (2^x)
    f32x2 av01 = {avf.x * LOG2E, avf.y * LOG2E};
    f32x2 av23 = {avf.z * LOG2E, avf.w * LOG2E};

    ushort4 xrv = *(const ushort4*)(xr + (long)n * OUTD + j0);
    f32x2 xr01 = {bf2f(xrv.x), bf2f(xrv.y)};
    f32x2 xr23 = {bf2f(xrv.z), bf2f(xrv.w)};

    int beg = off[n], end = off[n + 1];

    float s = 0.f;
    f32x2 a01 = {0.f, 0.f}, a23 = {0.f, 0.f};

    // per-edge logit in log2 domain; also returns decoded fp8 pairs for reuse
    auto logit = [&](const int4& r, u32 v, f32x2& d0, f32x2& d1) -> float {
        d0 = __builtin_amdgcn_cvt_pk_f32_fp8((int)v, false);
        d1 = __builtin_amdgcn_cvt_pk_f32_fp8((int)v, true);
        f32x2 ea0 = {__int_as_float(r.y), __int_as_float(r.y)};
        f32x2 ea1 = {__int_as_float(r.z), __int_as_float(r.z)};
        f32x2 ea2 = {__int_as_float(r.w), __int_as_float(r.w)};
        f32x2 t01 = d0 + xr01;
        t01 = __builtin_elementwise_fma(ea0, w0_01, t01);
        t01 = __builtin_elementwise_fma(ea1, w1_01, t01);
        t01 = __builtin_elementwise_fma(ea2, w2_01, t01);
        f32x2 t23 = d1 + xr23;
        t23 = __builtin_elementwise_fma(ea0, w0_23, t23);
        t23 = __builtin_elementwise_fma(ea1, w1_23, t23);
        t23 = __builtin_elementwise_fma(ea2, w2_23, t23);
        f32x2 l01 = __builtin_elementwise_max(t01, 0.2f * t01);
        f32x2 l23 = __builtin_elementwise_max(t23, 0.2f * t23);
        f32x2 pv = l01 * av01;
        pv = __builtin_elementwise_fma(l23, av23, pv);
        return pv[0] + pv[1];
    };

    if (beg < end) {
        int4 r0, r1, r2, r3;
        u32 v0, v1, v2, v3;
        {
            int i1 = min(beg + 1, end - 1), i2 = min(beg + 2, end - 1), i3 = min(beg + 3, end - 1);
            r0 = erec[beg]; r1 = erec[i1]; r2 = erec[i2]; r3 = erec[i3];
            v0 = *(const u32*)(xl8 + (long)r0.x * OUTD + j0);
            v1 = *(const u32*)(xl8 + (long)r1.x * OUTD + j0);
            v2 = *(const u32*)(xl8 + (long)r2.x * OUTD + j0);
            v3 = *(const u32*)(xl8 + (long)r3.x * OUTD + j0);
        }
#pragma unroll 1
        for (int i = beg; i < end; i += 4) {
            // prefetch next iteration (clamped; harmless dup reads on tail)
            int nb = i + 4;
            int p0i = min(nb, end - 1), p1i = min(nb + 1, end - 1);
            int p2i = min(nb + 2, end - 1), p3i = min(nb + 3, end - 1);
            int4 nr0 = erec[p0i], nr1 = erec[p1i], nr2 = erec[p2i], nr3 = erec[p3i];
            u32 nv0 = *(const u32*)(xl8 + (long)nr0.x * OUTD + j0);
            u32 nv1 = *(const u32*)(xl8 + (long)nr1.x * OUTD + j0);
            u32 nv2 = *(const u32*)(xl8 + (long)nr2.x * OUTD + j0);
            u32 nv3 = *(const u32*)(xl8 + (long)nr3.x * OUTD + j0);

            f32x2 d00, d01, d10, d11, d20, d21, d30, d31;
            float p0 = logit(r0, v0, d00, d01);
            float p1 = logit(r1, v1, d10, d11);
            float p2 = logit(r2, v2, d20, d21);
            float p3 = logit(r3, v3, d30, d31);

            p0 = wave_sum_bcast(p0);
            p1 = wave_sum_bcast(p1);
            p2 = wave_sum_bcast(p2);
            p3 = wave_sum_bcast(p3);
            if (i + 1 >= end) p1 = -1.0e30f;   // exp2 -> 0
            if (i + 2 >= end) p2 = -1.0e30f;
            if (i + 3 >= end) p3 = -1.0e30f;

            float e0 = __builtin_amdgcn_exp2f(p0);
            float e1 = __builtin_amdgcn_exp2f(p1);
            float e2 = __builtin_amdgcn_exp2f(p2);
            float e3 = __builtin_amdgcn_exp2f(p3);
            s += (e0 + e1) + (e2 + e3);

            f32x2 e0v = {e0, e0}, e1v = {e1, e1}, e2v = {e2, e2}, e3v = {e3, e3};
            a01 = __builtin_elementwise_fma(e0v, d00, a01);
            a23 = __builtin_elementwise_fma(e0v, d01, a23);
            a01 = __builtin_elementwise_fma(e1v, d10, a01);
            a23 = __builtin_elementwise_fma(e1v, d11, a23);
            a01 = __builtin_elementwise_fma(e2v, d20, a01);
            a23 = __builtin_elementwise_fma(e2v, d21, a23);
            a01 = __builtin_elementwise_fma(e3v, d30, a01);
            a23 = __builtin_elementwise_fma(e3v, d31, a23);

            r0 = nr0; r1 = nr1; r2 = nr2; r3 = nr3;
            v0 = nv0; v1 = nv1; v2 = nv2; v3 = nv3;
        }
    }

    float inv = (end > beg) ? 1.f / s : 0.f;

    ushort4 hv = *(const ushort4*)(hres + (long)n * OUTD + j0);
    float h0 = fmaxf(fmaf(a01[0], inv, bf2f(hv.x)), 0.f);
    float h1 = fmaxf(fmaf(a01[1], inv, bf2f(hv.y)), 0.f);
    float h2 = fmaxf(fmaf(a23[0], inv, bf2f(hv.z)), 0.f);
    float h3 = fmaxf(fmaf(a23[1], inv, bf2f(hv.w)), 0.f);

    float sum = h0 + h1 + h2 + h3;
    float sq = h0 * h0 + h1 * h1 + h2 * h2 + h3 * h3;
    sum = wave_sum_bcast(sum);
    sq = wave_sum_bcast(sq);
    float mu = sum * (1.f / OUTD);
    float var = sq * (1.f / OUTD) - mu * mu;
    float rs = rsqrtf(fmaxf(var, 0.f) + 1e-5f);

    float4 gv = *(const float4*)(g2 + j0);
    float4 bv = *(const float4*)(be2 + j0);
    ushort4 yy;
    yy.x = f2bf((h0 - mu) * rs * gv.x + bv.x);
    yy.y = f2bf((h1 - mu) * rs * gv.y + bv.y);
    yy.z = f2bf((h2 - mu) * rs * gv.z + bv.z);
    yy.w = f2bf((h3 - mu) * rs * gv.w + bv.w);
    *(ushort4*)(&ylds[wid][j0]) = yy;
    __syncthreads();

    // ===== head: q = y @ Wq + bq via one MFMA pass (wave0: cols 0-15, wave1: cols 16-19) =====
    if (wid < 2) {
        int row = lane & 15, qd = lane >> 4;
        const u16* ab = &ylds[row & 3][qd * 8];   // rows 4-15 duplicate rows 0-3 (unused C rows)
        f32x4 cacc = {0.f, 0.f, 0.f, 0.f};
#pragma unroll
        for (int kk = 0; kk < 8; kk++) {
            bf16x8 afrag = *(const bf16x8*)(ab + kk * 32);
            bf16x8 bfrag = *(const bf16x8*)(wqB + ((((wid << 3) + kk) << 6) + lane) * 8);
            cacc = __builtin_amdgcn_mfma_f32_16x16x32_bf16(afrag, bfrag, cacc, 0, 0, 0);
        }
        // C layout: col=lane&15, row=(lane>>4)*4+g; lanes 0-15 hold rows(=nodes) 0-3 in g
        if (lane < 16) {
            int q = wid * 16 + lane;
            if (q < N_ACT) {
                float bqv = bq[q];
                long nb = (long)blockIdx.x * 4;
#pragma unroll
                for (int g = 0; g < 4; g++)
                    out[(nb + g) * N_ACT + q] = cacc[g] + bqv;
            }
        }
    }
}

extern "C" void kernel_launch(void* const* d_in, const int* in_sizes, int n_in,
                              void* d_out, int out_size, void* d_ws, size_t ws_size,
                              hipStream_t stream) {
    (void)in_sizes; (void)n_in; (void)out_size; (void)ws_size;
    const float* inp  = (const float*)d_in[0];
    const int*   ei   = (const int*)d_in[1];
    const float* ea   = (const float*)d_in[2];
    const float* W0   = (const float*)d_in[3];
    const float* b0   = (const float*)d_in[4];
    const float* g0   = (const float*)d_in[5];
    const float* be0  = (const float*)d_in[6];
    const float* W1   = (const float*)d_in[7];
    const float* b1   = (const float*)d_in[8];
    const float* g1   = (const float*)d_in[9];
    const float* be1  = (const float*)d_in[10];
    const float* Wl   = (const float*)d_in[11];
    const float* bl   = (const float*)d_in[12];
    const float* Wr   = (const float*)d_in[13];
    const float* br   = (const float*)d_in[14];
    const float* We   = (const float*)d_in[15];
    const float* att  = (const float*)d_in[16];
    const float* Wres = (const float*)d_in[17];
    const float* gbias= (const float*)d_in[18];
    const float* g2   = (const float*)d_in[19];
    const float* be2  = (const float*)d_in[20];
    const float* Wq   = (const float*)d_in[21];
    const float* bq   = (const float*)d_in[22];
    float* out = (float*)d_out;

    char* ws = (char*)d_ws;
    size_t o = 0;
    auto alloc = [&](size_t bytes) -> void* {
        void* p = ws + o;
        o += (bytes + 255) & ~(size_t)255;
        return p;
    };
    u8*    xl8    = (u8*)   alloc((size_t)N_NODES * OUTD);        // 16 MiB (fp8 e4m3)
    u16*   xr     = (u16*)  alloc((size_t)N_NODES * OUTD * 2);    // 32 MiB
    u16*   hres   = (u16*)  alloc((size_t)N_NODES * OUTD * 2);    // 32 MiB
    int*   deg    = (int*)  alloc((size_t)N_NODES * 4);           // 256 KiB
    int*   off    = (int*)  alloc((size_t)(N_NODES + 1) * 4);
    int*   rank   = (int*)  alloc((size_t)N_EDGES * 4);           // 4 MiB (edge slot from deg pass)
    int4*  erec   = (int4*) alloc((size_t)N_EDGES * 16);          // 16 MiB
    u16*   wt     = (u16*)  alloc((size_t)768 * HID * 2);         // 192 KiB  gat [768][128]
    u16*   wt0    = (u16*)  alloc((size_t)HID * IN_DIM * 2);      // 24 KiB   W0^T [128][96]
    u16*   wt1    = (u16*)  alloc((size_t)HID * HID * 2);         // 32 KiB   W1^T [128][128]
    u16*   wqB    = (u16*)  alloc((size_t)2 * 8 * 64 * 8 * 2);    // 16 KiB   Wq MFMA B-frags

    k_prep<<<784, 256, 0, stream>>>(deg, Wl, Wr, Wres, wt, W0, wt0, W1, wt1, Wq, wqB);
    k_fused<<<512 + N_EDGES / 256, 256, 0, stream>>>(inp, wt0, wt1, wt,
        b0, g0, be0, b1, g1, be1, bl, br, gbias, ei, deg, rank, xl8, xr, hres);
    k_scan<<<1, 1024, 0, stream>>>(deg, off);
    k_scatter<<<N_EDGES / 256, 256, 0, stream>>>(ei, ea, off, rank, erec);
    k_agg_fused<<<N_NODES / 4, 256, 0, stream>>>(off, erec, xl8, xr, hres, We, att, g2, be2, wqB, bq, out);
}